// Round 11
// baseline (27.641 us; speedup 1.0000x reference)
//
#include <hip/hip_runtime.h>
#include <math.h>

#define S_ 4
#define NLAB 16
#define C1 32
#define C2 64
#define N_ 512
#define RC 6.0f
#define PI_OVER_RC 0.5235987755982988f  // pi/6
#define SEGCAP 32   // per-wave-quarter neighbor cap (mean ~8, passed at 32 in R10)
#define APB 4       // atoms per block, processed sequentially (pipeline compute vs drain)

// 512 blocks x 4 waves; block handles APB consecutive atoms with the 4-wave coop
// structure per atom. Stores of atom k drain while atom k+1 computes.
__global__ __launch_bounds__(256, 4) void desc_kernel(
    const int* __restrict__ numbers,    // [B,N]
    const float* __restrict__ coords,   // [B,N,3]
    const float* __restrict__ nuww0, const float* __restrict__ sigmas0,
    const float* __restrict__ centres0, // [16,32]
    const float* __restrict__ nuww1, const float* __restrict__ sigmas1,
    const float* __restrict__ centres1, // [16,64]
    float* __restrict__ out)            // [B,N,4096]
{
    __shared__ float s_c0[NLAB * 33];        // stride-33: conflict-free
    __shared__ float s_c1[NLAB * C2];
    __shared__ float s_ww0[NLAB], s_sg0[NLAB], s_ww1[NLAB], s_sg1[NLAB];
    __shared__ float4 s_pair[4][SEGCAP];     // per-wave segment
    __shared__ float  s_s1[4][SEGCAP];
    __shared__ int    s_lab[4][SEGCAP];
    __shared__ float4 s_part[4][C2];         // per-wave partial Lm
    __shared__ float4 s_Lm[C2];

    const int tid  = threadIdx.x;
    const int wq   = tid >> 6;               // wave 0..3 = j-quarter
    const int lane = tid & 63;

    // ---- stage params once per block ----
    for (int idx = tid; idx < NLAB * C1; idx += 256) {
        int l = idx >> 5, c = idx & 31;
        s_c0[l * 33 + c] = centres0[idx];
    }
    for (int idx = tid; idx < NLAB * C2; idx += 256) s_c1[idx] = centres1[idx];
    if (tid < NLAB) {
        s_ww0[tid] = nuww0[tid]; s_sg0[tid] = sigmas0[tid];
        s_ww1[tid] = nuww1[tid]; s_sg1[tid] = sigmas1[tid];
    }
    __syncthreads();

    #pragma unroll 1
    for (int a = 0; a < APB; ++a) {
        const int bi   = blockIdx.x * APB + a;   // b*N + i
        const int b    = bi >> 9;
        const int i    = bi & (N_ - 1);
        const int base = b * N_;
        if (a) __syncthreads();                  // guard s_part/s_Lm reuse

        const float xi = coords[(base + i) * 3 + 0];
        const float yi = coords[(base + i) * 3 + 1];
        const float zi = coords[(base + i) * 3 + 2];
        const int zlab = numbers[base + i] * S_;

        // ---- scan own j-quarter, ballot-compact (deterministic, j-ordered) ----
        int cntq = 0;
        #pragma unroll
        for (int t = 0; t < 2; ++t) {
            int j = wq * 128 + t * 64 + lane;
            float dx = coords[(base + j) * 3 + 0] - xi;
            float dy = coords[(base + j) * 3 + 1] - yi;
            float dz = coords[(base + j) * 3 + 2] - zi;
            int   zj = numbers[base + j];
            float d2 = dx * dx + dy * dy + dz * dz;
            float d  = sqrtf(d2);                // match ref: test rounded d
            bool hit = (j != i) && (d <= RC);
            unsigned long long m = __ballot(hit);
            int slot = cntq + __popcll(m & ((1ull << lane) - 1ull));
            if (hit && slot < SEGCAP) {
                s_pair[wq][slot] = make_float4(dx, dy, dz, d);
                s_lab[wq][slot]  = zlab + zj;
            }
            cntq += __popcll(m);
        }
        const int nnq = min(cntq, SEGCAP);
        __builtin_amdgcn_wave_barrier();

        // ---- pass B: lane-per-pair on own segment ----
        if (lane < nnq) {
            float4 g  = s_pair[wq][lane];
            int   lab = s_lab[wq][lane];
            float fc  = 0.5f * __cosf(g.w * PI_OVER_RC) + 0.5f;
            float sg0 = s_sg0[lab];
            const float* c0 = &s_c0[lab * 33];
            float p0 = 0.f, p1 = 0.f;
            #pragma unroll
            for (int c = 0; c < C1; c += 2) {
                float a0_ = (fc - c0[c])     * sg0;
                float a1_ = (fc - c0[c + 1]) * sg0;
                p0 += __expf(-(a0_ * a0_));
                p1 += __expf(-(a1_ * a1_));
            }
            float fac = (g.w > 0.f) ? (fc / g.w) : 0.f;
            s_pair[wq][lane] = make_float4(fc, g.x * fac, g.y * fac, g.z * fac);
            s_s1[wq][lane]   = s_ww0[lab] * (p0 + p1);
        }
        __builtin_amdgcn_wave_barrier();

        // ---- phase 2: lane = channel; iterate own segment (~8 iters avg) ----
        {
            float a0 = 0.f, a1 = 0.f, a2 = 0.f, a3 = 0.f;
            for (int k = 0; k < nnq; ++k) {
                int    lab = s_lab[wq][k];       // broadcast
                float  s1  = s_s1[wq][k];        // broadcast
                float4 r4  = s_pair[wq][k];      // broadcast
                float  al  = (s1 - s_c1[lab * C2 + lane]) * s_sg1[lab];
                float  p   = s_ww1[lab] * __expf(-(al * al));
                a0 += p * r4.x; a1 += p * r4.y; a2 += p * r4.z; a3 += p * r4.w;
            }
            s_part[wq][lane] = make_float4(a0, a1, a2, a3);
        }
        __syncthreads();                          // partials visible block-wide

        // ---- combine partials (redundant per wave) ----
        float4 P0 = s_part[0][lane], P1 = s_part[1][lane];
        float4 P2 = s_part[2][lane], P3 = s_part[3][lane];
        float a0 = (P0.x + P1.x) + (P2.x + P3.x);
        float a1 = (P0.y + P1.y) + (P2.y + P3.y);
        float a2 = (P0.z + P1.z) + (P2.z + P3.z);
        float a3 = (P0.w + P1.w) + (P2.w + P3.w);
        s_Lm[lane] = make_float4(a0, a1, a2, a3); // identical values from all waves

        // ---- ||R||_F^2 = ||L^T L||_F^2 via 4x4 Gram wave-reduce ----
        float g00 = a0 * a0, g01 = a0 * a1, g02 = a0 * a2, g03 = a0 * a3;
        float g11 = a1 * a1, g12 = a1 * a2, g13 = a1 * a3;
        float g22 = a2 * a2, g23 = a2 * a3, g33 = a3 * a3;
        #pragma unroll
        for (int off = 32; off >= 1; off >>= 1) {
            g00 += __shfl_xor(g00, off, 64); g01 += __shfl_xor(g01, off, 64);
            g02 += __shfl_xor(g02, off, 64); g03 += __shfl_xor(g03, off, 64);
            g11 += __shfl_xor(g11, off, 64); g12 += __shfl_xor(g12, off, 64);
            g13 += __shfl_xor(g13, off, 64); g22 += __shfl_xor(g22, off, 64);
            g23 += __shfl_xor(g23, off, 64); g33 += __shfl_xor(g33, off, 64);
        }
        float ss = g00 * g00 + g11 * g11 + g22 * g22 + g33 * g33
                 + 2.f * (g01 * g01 + g02 * g02 + g03 * g03
                        + g12 * g12 + g13 * g13 + g23 * g23);
        float inv = rsqrtf(ss);                   // ss==0 -> NaN, same as ref 0/0
        __builtin_amdgcn_wave_barrier();          // own s_Lm writes ordered

        // ---- epilogue: wave wq stores rows [wq*16, wq*16+16) = 4 KB, coalesced;
        //      fire-and-forget: drains while next atom computes ----
        const int cb = (lane & 15) * 4;
        float4 Lc0 = s_Lm[cb + 0], Lc1 = s_Lm[cb + 1];
        float4 Lc2 = s_Lm[cb + 2], Lc3 = s_Lm[cb + 3];
        Lc0.x *= inv; Lc0.y *= inv; Lc0.z *= inv; Lc0.w *= inv;
        Lc1.x *= inv; Lc1.y *= inv; Lc1.z *= inv; Lc1.w *= inv;
        Lc2.x *= inv; Lc2.y *= inv; Lc2.z *= inv; Lc2.w *= inv;
        Lc3.x *= inv; Lc3.y *= inv; Lc3.z *= inv; Lc3.w *= inv;
        float* po = out + (size_t)bi * (C2 * C2);
        #pragma unroll
        for (int t = 0; t < 4; ++t) {
            int q  = wq * 4 + t;
            int dd = q * 4 + (lane >> 4);
            float4 Ld = s_Lm[dd];                 // multicast
            float4 v;
            v.x = Lc0.x * Ld.x + Lc0.y * Ld.y + Lc0.z * Ld.z + Lc0.w * Ld.w;
            v.y = Lc1.x * Ld.x + Lc1.y * Ld.y + Lc1.z * Ld.z + Lc1.w * Ld.w;
            v.z = Lc2.x * Ld.x + Lc2.y * Ld.y + Lc2.z * Ld.z + Lc2.w * Ld.w;
            v.w = Lc3.x * Ld.x + Lc3.y * Ld.y + Lc3.z * Ld.z + Lc3.w * Ld.w;
            *reinterpret_cast<float4*>(po + q * 256 + lane * 4) = v;
        }
    }
}

extern "C" void kernel_launch(void* const* d_in, const int* in_sizes, int n_in,
                              void* d_out, int out_size, void* d_ws, size_t ws_size,
                              hipStream_t stream) {
    const int*   numbers  = (const int*)  d_in[1];
    const float* coords   = (const float*)d_in[2];
    const float* nuww0    = (const float*)d_in[3];
    const float* sigmas0  = (const float*)d_in[4];
    const float* centres0 = (const float*)d_in[5];
    const float* nuww1    = (const float*)d_in[6];
    const float* sigmas1  = (const float*)d_in[7];
    const float* centres1 = (const float*)d_in[8];
    float* out = (float*)d_out;

    const int B = in_sizes[1] / N_;           // 4
    dim3 grid(B * N_ / APB), block(256);      // 512 blocks, 4 sequential atoms each
    desc_kernel<<<grid, block, 0, stream>>>(numbers, coords, nuww0, sigmas0,
                                            centres0, nuww1, sigmas1, centres1, out);
}

// Round 12
// 21.781 us; speedup vs baseline: 1.2690x; 1.2690x over previous
//
#include <hip/hip_runtime.h>
#include <math.h>

#define S_ 4
#define NLAB 16
#define C1 32
#define C2 64
#define N_ 512
#define RC 6.0f
#define PI_OVER_RC 0.5235987755982988f  // pi/6
#define SEGCAP 24   // per-(quarter,bucket) cap; mean ~2, Poisson tail << 24

// 1 block = 1 atom, 4 waves. Scan buckets neighbors by zj (label = zlab+zj);
// phase 2: wave w owns bucket w with its c1 row hoisted to registers.
__global__ __launch_bounds__(256, 4) void desc_kernel(
    const int* __restrict__ numbers,    // [B,N]
    const float* __restrict__ coords,   // [B,N,3]
    const float* __restrict__ nuww0, const float* __restrict__ sigmas0,
    const float* __restrict__ centres0, // [16,32]
    const float* __restrict__ nuww1, const float* __restrict__ sigmas1,
    const float* __restrict__ centres1, // [16,64]
    float* __restrict__ out)            // [B,N,4096]
{
    __shared__ float s_c0[NLAB * 33];        // stride-33: conflict-free for 4-label reads
    __shared__ float s_c1[NLAB * C2];
    __shared__ float s_ww0[NLAB], s_sg0[NLAB], s_ww1[NLAB], s_sg1[NLAB];
    __shared__ float4 s_pair[4][4][SEGCAP];  // [quarter][bucket]: (dx,dy,dz,d)->(fc,ax,ay,az)
    __shared__ float  s_s1[4][4][SEGCAP];
    __shared__ int    s_segcnt[4][4];        // [quarter][bucket]
    __shared__ float4 s_part[4][C2];         // per-bucket-wave partial Lm
    __shared__ float4 s_Lm[C2];

    const int tid  = threadIdx.x;
    const int wq   = tid >> 6;               // wave = j-quarter (scan/passB) = bucket (phase2)
    const int lane = tid & 63;
    const int bi   = blockIdx.x;             // b*N + i
    const int b    = bi >> 9;
    const int i    = bi & (N_ - 1);
    const int base = b * N_;

    // ---- early register loads (overlap with scan; no LDS deps) ----
    const float xi = coords[(base + i) * 3 + 0];
    const float yi = coords[(base + i) * 3 + 1];
    const float zi = coords[(base + i) * 3 + 2];
    const int zlab = numbers[base + i] * S_;

    float4 rc0 = make_float4(0.f, 0.f, 0.f, 0.f);
    if (tid < 128) rc0 = reinterpret_cast<const float4*>(centres0)[tid];
    float4 rc1 = reinterpret_cast<const float4*>(centres1)[tid];
    float rsc = 0.f;
    if (tid < 64) {
        const float* sp = (tid < 16) ? nuww0 : (tid < 32) ? sigmas0
                        : (tid < 48) ? nuww1 : sigmas1;
        rsc = sp[tid & 15];
    }

    // ---- scan own j-quarter, bucket by zj, ballot compaction (deterministic) ----
    int cg[4] = {0, 0, 0, 0};
    const unsigned long long lmask = (1ull << lane) - 1ull;
    #pragma unroll
    for (int t = 0; t < 2; ++t) {
        int j = wq * 128 + t * 64 + lane;
        float dx = coords[(base + j) * 3 + 0] - xi;
        float dy = coords[(base + j) * 3 + 1] - yi;
        float dz = coords[(base + j) * 3 + 2] - zi;
        int   zj = numbers[base + j];
        float d2 = dx * dx + dy * dy + dz * dz;
        float d  = sqrtf(d2);                // match ref: test rounded d
        bool hit = (j != i) && (d <= RC);
        #pragma unroll
        for (int g = 0; g < 4; ++g) {
            unsigned long long m = __ballot(hit && (zj == g));
            if (hit && (zj == g)) {
                int slot = cg[g] + (int)__popcll(m & lmask);
                if (slot < SEGCAP) s_pair[wq][g][slot] = make_float4(dx, dy, dz, d);
            }
            cg[g] += (int)__popcll(m);
        }
    }
    if (lane == 0) {
        #pragma unroll
        for (int g = 0; g < 4; ++g) s_segcnt[wq][g] = min(cg[g], SEGCAP);
    }

    // ---- params registers -> LDS (loads issued long ago) ----
    if (tid < 128) {
        int idx = tid * 4, l = idx >> 5, c = idx & 31;   // c 4-aligned, never crosses row
        s_c0[l * 33 + c + 0] = rc0.x; s_c0[l * 33 + c + 1] = rc0.y;
        s_c0[l * 33 + c + 2] = rc0.z; s_c0[l * 33 + c + 3] = rc0.w;
    }
    s_c1[tid * 4 + 0] = rc1.x; s_c1[tid * 4 + 1] = rc1.y;
    s_c1[tid * 4 + 2] = rc1.z; s_c1[tid * 4 + 3] = rc1.w;
    if (tid < 64) {
        int r = tid & 15;
        if      (tid < 16) s_ww0[r] = rsc;
        else if (tid < 32) s_sg0[r] = rsc;
        else if (tid < 48) s_ww1[r] = rsc;
        else               s_sg1[r] = rsc;
    }
    __syncthreads();

    // ---- pass B: own quarter's segments flattened, lane-per-pair ----
    {
        const int n0 = min(cg[0], SEGCAP), n1 = min(cg[1], SEGCAP);
        const int n2 = min(cg[2], SEGCAP), n3 = min(cg[3], SEGCAP);
        const int p0 = n0, p1 = p0 + n1, p2 = p1 + n2, p3 = p2 + n3;
        for (int L = lane; L < p3; L += 64) {     // p3 <= 96; almost always 1 iter
            int g   = (L >= p0) + (L >= p1) + (L >= p2);
            int off = (g == 0) ? 0 : (g == 1) ? p0 : (g == 2) ? p1 : p2;
            int idx = L - off;
            float4 gv = s_pair[wq][g][idx];
            int   lab = zlab + g;
            float fc  = 0.5f * __cosf(gv.w * PI_OVER_RC) + 0.5f;
            float sg0 = s_sg0[lab];
            const float* c0p = &s_c0[lab * 33];
            float pa = 0.f, pb = 0.f;
            #pragma unroll
            for (int c = 0; c < C1; c += 2) {
                float a0_ = (fc - c0p[c])     * sg0;
                float a1_ = (fc - c0p[c + 1]) * sg0;
                pa += __expf(-(a0_ * a0_));
                pb += __expf(-(a1_ * a1_));
            }
            float fac = (gv.w > 0.f) ? (fc / gv.w) : 0.f;
            s_pair[wq][g][idx] = make_float4(fc, gv.x * fac, gv.y * fac, gv.z * fac);
            s_s1[wq][g][idx]   = s_ww0[lab] * (pa + pb);
        }
    }
    __syncthreads();

    // ---- phase 2: wave wq = bucket wq; c1 row hoisted, 1-level LDS per iter ----
    {
        const int   labw = zlab + wq;
        const float c1v  = s_c1[labw * C2 + lane];
        const float sg1  = s_sg1[labw];
        const float ww1  = s_ww1[labw];
        float a0 = 0.f, a1 = 0.f, a2 = 0.f, a3 = 0.f;
        #pragma unroll
        for (int q = 0; q < 4; ++q) {             // quarters in j-order: deterministic
            int nk = s_segcnt[q][wq];
            for (int k = 0; k < nk; ++k) {
                float  s1 = s_s1[q][wq][k];       // broadcast
                float4 r4 = s_pair[q][wq][k];     // broadcast
                float  al = (s1 - c1v) * sg1;
                float  p  = ww1 * __expf(-(al * al));
                a0 += p * r4.x; a1 += p * r4.y; a2 += p * r4.z; a3 += p * r4.w;
            }
        }
        s_part[wq][lane] = make_float4(a0, a1, a2, a3);
    }
    __syncthreads();

    // ---- combine partials (redundant per wave; no further block sync) ----
    float4 P0 = s_part[0][lane], P1 = s_part[1][lane];
    float4 P2 = s_part[2][lane], P3 = s_part[3][lane];
    float a0 = (P0.x + P1.x) + (P2.x + P3.x);
    float a1 = (P0.y + P1.y) + (P2.y + P3.y);
    float a2 = (P0.z + P1.z) + (P2.z + P3.z);
    float a3 = (P0.w + P1.w) + (P2.w + P3.w);
    s_Lm[lane] = make_float4(a0, a1, a2, a3);     // each wave writes full array (same values)

    // ---- ||R||_F^2 = ||L^T L||_F^2 via 4x4 Gram wave-reduce ----
    float g00 = a0 * a0, g01 = a0 * a1, g02 = a0 * a2, g03 = a0 * a3;
    float g11 = a1 * a1, g12 = a1 * a2, g13 = a1 * a3;
    float g22 = a2 * a2, g23 = a2 * a3, g33 = a3 * a3;
    #pragma unroll
    for (int off = 32; off >= 1; off >>= 1) {
        g00 += __shfl_xor(g00, off, 64); g01 += __shfl_xor(g01, off, 64);
        g02 += __shfl_xor(g02, off, 64); g03 += __shfl_xor(g03, off, 64);
        g11 += __shfl_xor(g11, off, 64); g12 += __shfl_xor(g12, off, 64);
        g13 += __shfl_xor(g13, off, 64); g22 += __shfl_xor(g22, off, 64);
        g23 += __shfl_xor(g23, off, 64); g33 += __shfl_xor(g33, off, 64);
    }
    float ss = g00 * g00 + g11 * g11 + g22 * g22 + g33 * g33
             + 2.f * (g01 * g01 + g02 * g02 + g03 * g03
                    + g12 * g12 + g13 * g13 + g23 * g23);
    float inv = rsqrtf(ss);                       // ss==0 -> NaN, same as ref 0/0
    __builtin_amdgcn_wave_barrier();              // order own s_Lm writes before reads

    // ---- epilogue: wave wq writes rows [wq*16, wq*16+16) = 4 KB, dwordx4 ----
    const int cb = (lane & 15) * 4;
    float4 Lc0 = s_Lm[cb + 0], Lc1 = s_Lm[cb + 1];
    float4 Lc2 = s_Lm[cb + 2], Lc3 = s_Lm[cb + 3];
    Lc0.x *= inv; Lc0.y *= inv; Lc0.z *= inv; Lc0.w *= inv;
    Lc1.x *= inv; Lc1.y *= inv; Lc1.z *= inv; Lc1.w *= inv;
    Lc2.x *= inv; Lc2.y *= inv; Lc2.z *= inv; Lc2.w *= inv;
    Lc3.x *= inv; Lc3.y *= inv; Lc3.z *= inv; Lc3.w *= inv;
    float* po = out + (size_t)bi * (C2 * C2);
    #pragma unroll
    for (int t = 0; t < 4; ++t) {
        int q  = wq * 4 + t;
        int dd = q * 4 + (lane >> 4);
        float4 Ld = s_Lm[dd];                     // multicast
        float4 v;
        v.x = Lc0.x * Ld.x + Lc0.y * Ld.y + Lc0.z * Ld.z + Lc0.w * Ld.w;
        v.y = Lc1.x * Ld.x + Lc1.y * Ld.y + Lc1.z * Ld.z + Lc1.w * Ld.w;
        v.z = Lc2.x * Ld.x + Lc2.y * Ld.y + Lc2.z * Ld.z + Lc2.w * Ld.w;
        v.w = Lc3.x * Ld.x + Lc3.y * Ld.y + Lc3.z * Ld.z + Lc3.w * Ld.w;
        *reinterpret_cast<float4*>(po + q * 256 + lane * 4) = v;
    }
}

extern "C" void kernel_launch(void* const* d_in, const int* in_sizes, int n_in,
                              void* d_out, int out_size, void* d_ws, size_t ws_size,
                              hipStream_t stream) {
    const int*   numbers  = (const int*)  d_in[1];
    const float* coords   = (const float*)d_in[2];
    const float* nuww0    = (const float*)d_in[3];
    const float* sigmas0  = (const float*)d_in[4];
    const float* centres0 = (const float*)d_in[5];
    const float* nuww1    = (const float*)d_in[6];
    const float* sigmas1  = (const float*)d_in[7];
    const float* centres1 = (const float*)d_in[8];
    float* out = (float*)d_out;

    const int B = in_sizes[1] / N_;           // 4
    dim3 grid(B * N_), block(256);            // 1 atom per block, 4 waves
    desc_kernel<<<grid, block, 0, stream>>>(numbers, coords, nuww0, sigmas0,
                                            centres0, nuww1, sigmas1, centres1, out);
}